// Round 2
// baseline (727.674 us; speedup 1.0000x reference)
//
#include <hip/hip_runtime.h>
#include <hip/hip_bf16.h>

// ---------------------------------------------------------------------------
// GRACE contrastive loss, MI355X.
//  out = mean_k 0.5*(log d1_k + log d2_k) - s12[k,k]/tau
//  d1_k = sum_j exp(s11/t) + sum_j exp(s12/t) - exp(s11_kk/t)
//  d2_k = sum_j exp(s22/t) + sum_j exp(s21/t) - exp(s22_kk/t)
// With M=[n1;n2] (24576x256) everything is row sums of exp(M M^T / tau)
// split by j-half, plus diagonal probes.
//
// R2: sim_kernel restructured — A fragments in registers (loaded once from
// global), B staged per 128-row j-tile (full K) with 2 barriers per 128
// MFMAs, bank-swizzle fixed (blk ^= row&31 at 512B row stride).
// ---------------------------------------------------------------------------

#define NROWS 12288
#define TWO_N 24576
#define KDIM 256
#define BM 128
#define BN 128
#define BK 32
#define BJ 128
#define NCHUNK 4
#define JCHUNK (TWO_N / NCHUNK) /* 6144 */
#define LOG2E 1.4426950408889634f
#define TWOLOG2E 2.8853900817779268f /* (1/tau)*log2(e), tau=0.5 */

#if __has_builtin(__builtin_amdgcn_exp2f)
#define EXP2F(x) __builtin_amdgcn_exp2f(x)
#else
#define EXP2F(x) exp2f(x)
#endif

typedef __bf16 bf16x8 __attribute__((ext_vector_type(8)));
typedef __bf16 bf16x4v __attribute__((ext_vector_type(4)));
typedef float f32x4 __attribute__((ext_vector_type(4)));

typedef const __attribute__((address_space(1))) void* gptr_t;
typedef __attribute__((address_space(3))) void* lptr_t;

// ======== legacy 128x128 GEMM core (used by proj1/proj2 only) =============
__device__ __forceinline__ void stage_slab(const __bf16* g, int row0, int kelem,
                                           __bf16* lds, int w, int l) {
#pragma unroll
  for (int t = 0; t < 2; ++t) {
    int chunk = w * 2 + t;
    int r = chunk * 16 + (l >> 2);
    int c = l & 3;
    int src = c ^ (r & 3);
    const __bf16* ga = g + (size_t)(row0 + r) * KDIM + kelem + src * 8;
    __bf16* la = lds + chunk * 512;
    __builtin_amdgcn_global_load_lds((gptr_t)ga, (lptr_t)la, 16, 0, 0);
  }
}

__device__ __forceinline__ bf16x8 read_frag(const __bf16* lds, int rowbase,
                                            int tile, int l) {
  int r = rowbase + tile * 16 + (l & 15);
  int q = l >> 4;
  int blk = q ^ (r & 3);
  return *(const bf16x8*)(lds + r * 32 + blk * 8);
}

__device__ __forceinline__ void gemm_tile_core(const __bf16* A, int arow0,
                                               const __bf16* B, int brow0,
                                               __bf16* As, __bf16* Bs,
                                               f32x4 (&acc)[4][4], int w, int l) {
  const int warow = (w >> 1) * 64;
  const int wbrow = (w & 1) * 64;
#pragma unroll
  for (int ks = 0; ks < KDIM / BK; ++ks) {
    __syncthreads();
    stage_slab(A, arow0, ks * BK, As, w, l);
    stage_slab(B, brow0, ks * BK, Bs, w, l);
    __syncthreads();
    bf16x8 aF[4], bF[4];
#pragma unroll
    for (int mi = 0; mi < 4; ++mi) aF[mi] = read_frag(As, warow, mi, l);
#pragma unroll
    for (int ni = 0; ni < 4; ++ni) bF[ni] = read_frag(Bs, wbrow, ni, l);
#pragma unroll
    for (int mi = 0; mi < 4; ++mi)
#pragma unroll
      for (int ni = 0; ni < 4; ++ni)
        acc[mi][ni] = __builtin_amdgcn_mfma_f32_16x16x32_bf16(
            aF[mi], bF[ni], acc[mi][ni], 0, 0, 0);
  }
}

// ---------------------------------------------------------------------------
__global__ void cast_kernel(const float* __restrict__ src,
                            __bf16* __restrict__ dst, int n4) {
  int i = blockIdx.x * blockDim.x + threadIdx.x;
  if (i >= n4) return;
  float4 v = *(const float4*)(src + (size_t)i * 4);
  bf16x4v o;
  o[0] = (__bf16)v.x; o[1] = (__bf16)v.y; o[2] = (__bf16)v.z; o[3] = (__bf16)v.w;
  *(bf16x4v*)(dst + (size_t)i * 4) = o;
}

// T = ELU(Z @ W1^T + b1), stored bf16
__global__ __launch_bounds__(256, 2) void proj1_kernel(
    const __bf16* __restrict__ Zb, const __bf16* __restrict__ W1b,
    const float* __restrict__ b1, __bf16* __restrict__ Tb) {
  __shared__ __align__(16) __bf16 As[BM * BK];
  __shared__ __align__(16) __bf16 Bs[BN * BK];
  int w = threadIdx.x >> 6, l = threadIdx.x & 63;
  int i0 = blockIdx.x * BM, j0 = blockIdx.y * BN;
  int warow = (w >> 1) * 64, wbrow = (w & 1) * 64;
  f32x4 acc[4][4] = {};
  gemm_tile_core(Zb, i0, W1b, j0, As, Bs, acc, w, l);
  float bias[4];
#pragma unroll
  for (int ni = 0; ni < 4; ++ni) bias[ni] = b1[j0 + wbrow + ni * 16 + (l & 15)];
#pragma unroll
  for (int mi = 0; mi < 4; ++mi)
#pragma unroll
    for (int ni = 0; ni < 4; ++ni)
#pragma unroll
      for (int v = 0; v < 4; ++v) {
        int row = i0 + warow + mi * 16 + (l >> 4) * 4 + v;
        int col = j0 + wbrow + ni * 16 + (l & 15);
        float x = acc[mi][ni][v] + bias[ni];
        x = x > 0.f ? x : (EXP2F(x * LOG2E) - 1.f);  // ELU
        Tb[(size_t)row * KDIM + col] = (__bf16)x;
      }
}

// H = T @ W2^T + b2 (fp32), plus per-row sum of squares via atomics
__global__ __launch_bounds__(256, 2) void proj2_kernel(
    const __bf16* __restrict__ Tb, const __bf16* __restrict__ W2b,
    const float* __restrict__ b2, float* __restrict__ H,
    float* __restrict__ SS) {
  __shared__ __align__(16) __bf16 As[BM * BK];
  __shared__ __align__(16) __bf16 Bs[BN * BK];
  int w = threadIdx.x >> 6, l = threadIdx.x & 63;
  int i0 = blockIdx.x * BM, j0 = blockIdx.y * BN;
  int warow = (w >> 1) * 64, wbrow = (w & 1) * 64;
  f32x4 acc[4][4] = {};
  gemm_tile_core(Tb, i0, W2b, j0, As, Bs, acc, w, l);
  float bias[4];
#pragma unroll
  for (int ni = 0; ni < 4; ++ni) bias[ni] = b2[j0 + wbrow + ni * 16 + (l & 15)];
  float ss[4][4] = {};
#pragma unroll
  for (int mi = 0; mi < 4; ++mi)
#pragma unroll
    for (int ni = 0; ni < 4; ++ni)
#pragma unroll
      for (int v = 0; v < 4; ++v) {
        int row = i0 + warow + mi * 16 + (l >> 4) * 4 + v;
        int col = j0 + wbrow + ni * 16 + (l & 15);
        float x = acc[mi][ni][v] + bias[ni];
        H[(size_t)row * KDIM + col] = x;
        ss[mi][v] += x * x;
      }
#pragma unroll
  for (int mi = 0; mi < 4; ++mi)
#pragma unroll
    for (int v = 0; v < 4; ++v) {
      float x = ss[mi][v];
      x += __shfl_xor(x, 1, 64);
      x += __shfl_xor(x, 2, 64);
      x += __shfl_xor(x, 4, 64);
      x += __shfl_xor(x, 8, 64);
      if ((l & 15) == 0)
        atomicAdd(&SS[i0 + warow + mi * 16 + (l >> 4) * 4 + v], x);
    }
}

// Nb = H * rsqrt(SS[row]), bf16
__global__ void norm_kernel(const float* __restrict__ H,
                            const float* __restrict__ SS,
                            __bf16* __restrict__ Nb) {
  int i = blockIdx.x * blockDim.x + threadIdx.x;
  size_t idx = (size_t)i * 4;
  if (idx >= (size_t)TWO_N * KDIM) return;
  int row = (int)(idx >> 8);
  float inv = rsqrtf(SS[row]);
  float4 h = *(const float4*)(H + idx);
  bf16x4v o;
  o[0] = (__bf16)(h.x * inv); o[1] = (__bf16)(h.y * inv);
  o[2] = (__bf16)(h.z * inv); o[3] = (__bf16)(h.w * inv);
  *(bf16x4v*)(Nb + idx) = o;
}

// ======== R2 sim kernel ====================================================
// Row sums of exp(Nb Nb^T / tau), split by j-half; diagonal probes.
// A fragments (64 rows/wave x K=256) held in registers, loaded once from
// global (all L2/L3 hits). B: one 128-row x K=256 tile (64KB LDS) per jt,
// staged via global_load_lds w/ source-side XOR swizzle (blk ^ (row&31)).
__global__ __launch_bounds__(256, 2) void sim_kernel(
    const __bf16* __restrict__ Nb, float* __restrict__ Rlow,
    float* __restrict__ Rhigh, float* __restrict__ Dsame,
    float* __restrict__ Dcross) {
  __shared__ __align__(16) __bf16 Bs[BJ * KDIM];  // 65536 B
  int tid = threadIdx.x;
  int w = tid >> 6, l = tid & 63;
  int q = l >> 4;
  int i0 = blockIdx.x * BM;
  int chunk = blockIdx.y;
  int warow = (w >> 1) * 64;  // A rows of this wave: warow..warow+63
  int wbcol = (w & 1) * 64;   // B cols of this wave: wbcol..wbcol+63

  // ---- A fragments in registers: aF[mi][ks], 32 x bf16x8 = 128 VGPRs ----
  bf16x8 aF[4][8];
#pragma unroll
  for (int mi = 0; mi < 4; ++mi) {
    const __bf16* ap =
        Nb + (size_t)(i0 + warow + mi * 16 + (l & 15)) * KDIM + q * 8;
#pragma unroll
    for (int ks = 0; ks < 8; ++ks)
      aF[mi][ks] = *(const bf16x8*)(ap + ks * 32);
  }

  float rs[4][4] = {};  // running row sums (per mi, per v)

  for (int jt = 0; jt < JCHUNK / BJ; ++jt) {
    int j0 = chunk * JCHUNK + jt * BJ;
    __syncthreads();  // previous jt's reads of Bs done
    // stage 128 rows x 512B = 64KB; 64 chunks of 1KB (2 rows each)
#pragma unroll
    for (int t = 0; t < 16; ++t) {
      int ch = t * 4 + w;            // wave-uniform chunk id 0..63
      int r = ch * 2 + (l >> 5);     // row 0..127
      int c = l & 31;                // dest 16B-block within row
      int src = c ^ (r & 31);        // global k-block landing in slot c
      const __bf16* ga = Nb + (size_t)(j0 + r) * KDIM + src * 8;
      __bf16* la = Bs + ch * 512;    // wave-uniform base, 1KB/chunk
      __builtin_amdgcn_global_load_lds((gptr_t)ga, (lptr_t)la, 16, 0, 0);
    }
    __syncthreads();  // drains vmcnt

    f32x4 acc[4][4] = {};
#pragma unroll
    for (int ks = 0; ks < 8; ++ks) {
      bf16x8 bF[4];
#pragma unroll
      for (int ni = 0; ni < 4; ++ni) {
        int row = wbcol + ni * 16 + (l & 15);
        int kb = ks * 4 + q;
        int blk = kb ^ (row & 31);   // undo swizzle
        bF[ni] = *(const bf16x8*)(Bs + row * KDIM + blk * 8);
      }
#pragma unroll
      for (int mi = 0; mi < 4; ++mi)
#pragma unroll
        for (int ni = 0; ni < 4; ++ni)
          acc[mi][ni] = __builtin_amdgcn_mfma_f32_16x16x32_bf16(
              aF[mi][ks], bF[ni], acc[mi][ni], 0, 0, 0);
    }

    bool dsame = (j0 == i0);
    bool dcross = (j0 == i0 + NROWS);
#pragma unroll
    for (int mi = 0; mi < 4; ++mi)
#pragma unroll
      for (int ni = 0; ni < 4; ++ni)
#pragma unroll
        for (int v = 0; v < 4; ++v) {
          float s = acc[mi][ni][v];          // cosine (rows pre-normalized)
          rs[mi][v] += EXP2F(s * TWOLOG2E);  // exp(s/tau)
          if (dsame | dcross) {
            int li = warow + mi * 16 + q * 4 + v;
            int lj = wbcol + ni * 16 + (l & 15);
            if (li == lj) {
              if (dsame) Dsame[i0 + li] = s;
              else       Dcross[i0 + li] = s;
            }
          }
        }
  }

  // cross-lane (16-wide) reduce, one atomicAdd per row per wave
  float* R = (chunk >= NCHUNK / 2) ? Rhigh : Rlow;
#pragma unroll
  for (int mi = 0; mi < 4; ++mi)
#pragma unroll
    for (int v = 0; v < 4; ++v) {
      float x = rs[mi][v];
      x += __shfl_xor(x, 1, 64);
      x += __shfl_xor(x, 2, 64);
      x += __shfl_xor(x, 4, 64);
      x += __shfl_xor(x, 8, 64);
      if ((l & 15) == 0)
        atomicAdd(&R[i0 + warow + mi * 16 + q * 4 + v], x);
    }
}

__global__ void finalize_kernel(const float* __restrict__ Rlow,
                                const float* __restrict__ Rhigh,
                                const float* __restrict__ Dsame,
                                const float* __restrict__ Dcross,
                                float* __restrict__ out) {
  __shared__ float red[256];
  float acc = 0.f;
  for (int k = threadIdx.x; k < NROWS; k += 256) {
    float d1 = Rlow[k] + Rhigh[k] - EXP2F(Dsame[k] * TWOLOG2E);
    float d2 = Rhigh[NROWS + k] + Rlow[NROWS + k] -
               EXP2F(Dsame[NROWS + k] * TWOLOG2E);
    acc += 0.5f * (logf(d1) + logf(d2)) - 2.f * Dcross[k];
  }
  red[threadIdx.x] = acc;
  __syncthreads();
  for (int s = 128; s > 0; s >>= 1) {
    if (threadIdx.x < s) red[threadIdx.x] += red[threadIdx.x + s];
    __syncthreads();
  }
  if (threadIdx.x == 0) out[0] = red[0] / (float)NROWS;
}

// ---------------------------------------------------------------------------
extern "C" void kernel_launch(void* const* d_in, const int* in_sizes, int n_in,
                              void* d_out, int out_size, void* d_ws,
                              size_t ws_size, hipStream_t stream) {
  const float* z1 = (const float*)d_in[0];
  const float* z2 = (const float*)d_in[1];
  const float* W1 = (const float*)d_in[2];
  const float* b1 = (const float*)d_in[3];
  const float* W2 = (const float*)d_in[4];
  const float* b2 = (const float*)d_in[5];
  float* out = (float*)d_out;

  char* ws = (char*)d_ws;
  size_t off = 0;
  auto alloc = [&](size_t bytes) -> void* {
    void* p = ws + off;
    off += (bytes + 255) & ~(size_t)255;
    return p;
  };
  __bf16* Zb   = (__bf16*)alloc((size_t)TWO_N * KDIM * 2); // reused as Nb
  __bf16* W1b  = (__bf16*)alloc((size_t)KDIM * KDIM * 2);
  __bf16* W2b  = (__bf16*)alloc((size_t)KDIM * KDIM * 2);
  __bf16* Tb   = (__bf16*)alloc((size_t)TWO_N * KDIM * 2);
  float*  H    = (float*)alloc((size_t)TWO_N * KDIM * 4);
  float*  SS   = (float*)alloc((size_t)TWO_N * 4);
  float*  Rlow = (float*)alloc((size_t)TWO_N * 4);
  float*  Rhigh= (float*)alloc((size_t)TWO_N * 4);
  float*  Dsame= (float*)alloc((size_t)TWO_N * 4);
  float*  Dcross=(float*)alloc((size_t)NROWS * 4);
  __bf16* Nb = Zb;  // Zb dead after proj1

  hipMemsetAsync(SS, 0, (size_t)TWO_N * 4, stream);
  hipMemsetAsync(Rlow, 0, (size_t)TWO_N * 4, stream);
  hipMemsetAsync(Rhigh, 0, (size_t)TWO_N * 4, stream);

  int n4z = NROWS * KDIM / 4;   // 786432
  int n4w = KDIM * KDIM / 4;    // 16384
  cast_kernel<<<(n4z + 255) / 256, 256, 0, stream>>>(z1, Zb, n4z);
  cast_kernel<<<(n4z + 255) / 256, 256, 0, stream>>>(z2, Zb + (size_t)NROWS * KDIM, n4z);
  cast_kernel<<<(n4w + 255) / 256, 256, 0, stream>>>(W1, W1b, n4w);
  cast_kernel<<<(n4w + 255) / 256, 256, 0, stream>>>(W2, W2b, n4w);

  proj1_kernel<<<dim3(TWO_N / BM, KDIM / BN), 256, 0, stream>>>(Zb, W1b, b1, Tb);
  proj2_kernel<<<dim3(TWO_N / BM, KDIM / BN), 256, 0, stream>>>(Tb, W2b, b2, H, SS);

  int n4n = TWO_N * KDIM / 4;   // 1572864
  norm_kernel<<<(n4n + 255) / 256, 256, 0, stream>>>(H, SS, Nb);

  sim_kernel<<<dim3(TWO_N / BM, NCHUNK), 256, 0, stream>>>(Nb, Rlow, Rhigh,
                                                           Dsame, Dcross);
  finalize_kernel<<<1, 256, 0, stream>>>(Rlow, Rhigh, Dsame, Dcross, out);
}

// Round 3
// 542.421 us; speedup vs baseline: 1.3415x; 1.3415x over previous
//
#include <hip/hip_runtime.h>
#include <hip/hip_bf16.h>

// ---------------------------------------------------------------------------
// GRACE contrastive loss, MI355X.
//  out = mean_k 0.5*(log d1_k + log d2_k) - s12[k,k]/tau
//  d1_k = sum_j exp(s11/t) + sum_j exp(s12/t) - exp(s11_kk/t)
//  d2_k = sum_j exp(s22/t) + sum_j exp(s21/t) - exp(s22_kk/t)
// With M=[n1;n2] (24576x256) everything is row sums of exp(M M^T / tau)
// split by j-half, plus diagonal probes.
//
// R3: sim_kernel — (a) XCD-pinned j-chunks: NCHUNK=8, chunk=blockIdx&7 so
// each XCD's L2 permanently holds its chunk's 1.5MB B tile; (b) K-half
// software pipeline: stage 32KB half h+1 before computing half h, so every
// barrier's vmcnt drain covers loads issued a full 64-MFMA burst earlier.
// ---------------------------------------------------------------------------

#define NROWS 12288
#define TWO_N 24576
#define KDIM 256
#define BM 128
#define BN 128
#define BK 32
#define BJ 128
#define KHALF 128               /* elements per K-half */
#define NCHUNK 8
#define JCHUNK (TWO_N / NCHUNK) /* 3072 */
#define JTILES (JCHUNK / BJ)    /* 24 */
#define LOG2E 1.4426950408889634f
#define TWOLOG2E 2.8853900817779268f /* (1/tau)*log2(e), tau=0.5 */

#if __has_builtin(__builtin_amdgcn_exp2f)
#define EXP2F(x) __builtin_amdgcn_exp2f(x)
#else
#define EXP2F(x) exp2f(x)
#endif

typedef __bf16 bf16x8 __attribute__((ext_vector_type(8)));
typedef __bf16 bf16x4v __attribute__((ext_vector_type(4)));
typedef float f32x4 __attribute__((ext_vector_type(4)));

typedef const __attribute__((address_space(1))) void* gptr_t;
typedef __attribute__((address_space(3))) void* lptr_t;

// ======== legacy 128x128 GEMM core (used by proj1/proj2 only) =============
__device__ __forceinline__ void stage_slab(const __bf16* g, int row0, int kelem,
                                           __bf16* lds, int w, int l) {
#pragma unroll
  for (int t = 0; t < 2; ++t) {
    int chunk = w * 2 + t;
    int r = chunk * 16 + (l >> 2);
    int c = l & 3;
    int src = c ^ (r & 3);
    const __bf16* ga = g + (size_t)(row0 + r) * KDIM + kelem + src * 8;
    __bf16* la = lds + chunk * 512;
    __builtin_amdgcn_global_load_lds((gptr_t)ga, (lptr_t)la, 16, 0, 0);
  }
}

__device__ __forceinline__ bf16x8 read_frag(const __bf16* lds, int rowbase,
                                            int tile, int l) {
  int r = rowbase + tile * 16 + (l & 15);
  int q = l >> 4;
  int blk = q ^ (r & 3);
  return *(const bf16x8*)(lds + r * 32 + blk * 8);
}

__device__ __forceinline__ void gemm_tile_core(const __bf16* A, int arow0,
                                               const __bf16* B, int brow0,
                                               __bf16* As, __bf16* Bs,
                                               f32x4 (&acc)[4][4], int w, int l) {
  const int warow = (w >> 1) * 64;
  const int wbrow = (w & 1) * 64;
#pragma unroll
  for (int ks = 0; ks < KDIM / BK; ++ks) {
    __syncthreads();
    stage_slab(A, arow0, ks * BK, As, w, l);
    stage_slab(B, brow0, ks * BK, Bs, w, l);
    __syncthreads();
    bf16x8 aF[4], bF[4];
#pragma unroll
    for (int mi = 0; mi < 4; ++mi) aF[mi] = read_frag(As, warow, mi, l);
#pragma unroll
    for (int ni = 0; ni < 4; ++ni) bF[ni] = read_frag(Bs, wbrow, ni, l);
#pragma unroll
    for (int mi = 0; mi < 4; ++mi)
#pragma unroll
      for (int ni = 0; ni < 4; ++ni)
        acc[mi][ni] = __builtin_amdgcn_mfma_f32_16x16x32_bf16(
            aF[mi], bF[ni], acc[mi][ni], 0, 0, 0);
  }
}

// ---------------------------------------------------------------------------
__global__ void cast_kernel(const float* __restrict__ src,
                            __bf16* __restrict__ dst, int n4) {
  int i = blockIdx.x * blockDim.x + threadIdx.x;
  if (i >= n4) return;
  float4 v = *(const float4*)(src + (size_t)i * 4);
  bf16x4v o;
  o[0] = (__bf16)v.x; o[1] = (__bf16)v.y; o[2] = (__bf16)v.z; o[3] = (__bf16)v.w;
  *(bf16x4v*)(dst + (size_t)i * 4) = o;
}

// T = ELU(Z @ W1^T + b1), stored bf16
__global__ __launch_bounds__(256, 2) void proj1_kernel(
    const __bf16* __restrict__ Zb, const __bf16* __restrict__ W1b,
    const float* __restrict__ b1, __bf16* __restrict__ Tb) {
  __shared__ __align__(16) __bf16 As[BM * BK];
  __shared__ __align__(16) __bf16 Bs[BN * BK];
  int w = threadIdx.x >> 6, l = threadIdx.x & 63;
  int i0 = blockIdx.x * BM, j0 = blockIdx.y * BN;
  int warow = (w >> 1) * 64, wbrow = (w & 1) * 64;
  f32x4 acc[4][4] = {};
  gemm_tile_core(Zb, i0, W1b, j0, As, Bs, acc, w, l);
  float bias[4];
#pragma unroll
  for (int ni = 0; ni < 4; ++ni) bias[ni] = b1[j0 + wbrow + ni * 16 + (l & 15)];
#pragma unroll
  for (int mi = 0; mi < 4; ++mi)
#pragma unroll
    for (int ni = 0; ni < 4; ++ni)
#pragma unroll
      for (int v = 0; v < 4; ++v) {
        int row = i0 + warow + mi * 16 + (l >> 4) * 4 + v;
        int col = j0 + wbrow + ni * 16 + (l & 15);
        float x = acc[mi][ni][v] + bias[ni];
        x = x > 0.f ? x : (EXP2F(x * LOG2E) - 1.f);  // ELU
        Tb[(size_t)row * KDIM + col] = (__bf16)x;
      }
}

// H = T @ W2^T + b2 (fp32), plus per-row sum of squares via atomics
__global__ __launch_bounds__(256, 2) void proj2_kernel(
    const __bf16* __restrict__ Tb, const __bf16* __restrict__ W2b,
    const float* __restrict__ b2, float* __restrict__ H,
    float* __restrict__ SS) {
  __shared__ __align__(16) __bf16 As[BM * BK];
  __shared__ __align__(16) __bf16 Bs[BN * BK];
  int w = threadIdx.x >> 6, l = threadIdx.x & 63;
  int i0 = blockIdx.x * BM, j0 = blockIdx.y * BN;
  int warow = (w >> 1) * 64, wbrow = (w & 1) * 64;
  f32x4 acc[4][4] = {};
  gemm_tile_core(Tb, i0, W2b, j0, As, Bs, acc, w, l);
  float bias[4];
#pragma unroll
  for (int ni = 0; ni < 4; ++ni) bias[ni] = b2[j0 + wbrow + ni * 16 + (l & 15)];
  float ss[4][4] = {};
#pragma unroll
  for (int mi = 0; mi < 4; ++mi)
#pragma unroll
    for (int ni = 0; ni < 4; ++ni)
#pragma unroll
      for (int v = 0; v < 4; ++v) {
        int row = i0 + warow + mi * 16 + (l >> 4) * 4 + v;
        int col = j0 + wbrow + ni * 16 + (l & 15);
        float x = acc[mi][ni][v] + bias[ni];
        H[(size_t)row * KDIM + col] = x;
        ss[mi][v] += x * x;
      }
#pragma unroll
  for (int mi = 0; mi < 4; ++mi)
#pragma unroll
    for (int v = 0; v < 4; ++v) {
      float x = ss[mi][v];
      x += __shfl_xor(x, 1, 64);
      x += __shfl_xor(x, 2, 64);
      x += __shfl_xor(x, 4, 64);
      x += __shfl_xor(x, 8, 64);
      if ((l & 15) == 0)
        atomicAdd(&SS[i0 + warow + mi * 16 + (l >> 4) * 4 + v], x);
    }
}

// Nb = H * rsqrt(SS[row]), bf16
__global__ void norm_kernel(const float* __restrict__ H,
                            const float* __restrict__ SS,
                            __bf16* __restrict__ Nb) {
  int i = blockIdx.x * blockDim.x + threadIdx.x;
  size_t idx = (size_t)i * 4;
  if (idx >= (size_t)TWO_N * KDIM) return;
  int row = (int)(idx >> 8);
  float inv = rsqrtf(SS[row]);
  float4 h = *(const float4*)(H + idx);
  bf16x4v o;
  o[0] = (__bf16)(h.x * inv); o[1] = (__bf16)(h.y * inv);
  o[2] = (__bf16)(h.z * inv); o[3] = (__bf16)(h.w * inv);
  *(bf16x4v*)(Nb + idx) = o;
}

// ======== R3 sim kernel ====================================================
// grid = 1536 1D blocks. chunk = blockIdx&7 (XCD-pinned), itile = blockIdx>>3.
// A frags in registers (full K). B: 128 rows staged per jt in two 32KB
// K-halves, software-pipelined so each barrier drain covers loads issued one
// 64-MFMA burst earlier.
__global__ __launch_bounds__(256, 2) void sim_kernel(
    const __bf16* __restrict__ Nb, float* __restrict__ Rlow,
    float* __restrict__ Rhigh, float* __restrict__ Dsame,
    float* __restrict__ Dcross) {
  __shared__ __align__(16) __bf16 Bs[2 * BJ * KHALF];  // 2 x 32KB
  int tid = threadIdx.x;
  int w = tid >> 6, l = tid & 63;
  int q = l >> 4;
  int b = blockIdx.x;
  int chunk = b & 7;           // XCD id under round-robin dispatch
  int i0 = (b >> 3) * BM;
  int jbase = chunk * JCHUNK;
  int warow = (w >> 1) * 64;   // A rows of this wave
  int wbcol = (w & 1) * 64;    // B cols of this wave

  // stage one 32KB K-half of a 128-row j-tile; source-side XOR swizzle
  // (16 16B-blocks per row per half; blk' = blk ^ (row&15)).
  auto stage_half = [&](int jt, int half) {
    int j0 = jbase + jt * BJ;
#pragma unroll
    for (int t = 0; t < 8; ++t) {
      int ch = w * 8 + t;            // wave-uniform chunk 0..31 (1KB each)
      int r = ch * 4 + (l >> 4);     // row 0..127
      int c = l & 15;                // dest 16B-block slot
      int src = c ^ (r & 15);        // global k-block landing in slot c
      const __bf16* ga =
          Nb + (size_t)(j0 + r) * KDIM + half * KHALF + src * 8;
      __bf16* la = Bs + half * (BJ * KHALF) + ch * 512;  // uniform base
      __builtin_amdgcn_global_load_lds((gptr_t)ga, (lptr_t)la, 16, 0, 0);
    }
  };

  // ---- A fragments in registers: aF[mi][ks], 32 x bf16x8 = 128 VGPRs ----
  bf16x8 aF[4][8];
#pragma unroll
  for (int mi = 0; mi < 4; ++mi) {
    const __bf16* ap =
        Nb + (size_t)(i0 + warow + mi * 16 + (l & 15)) * KDIM + q * 8;
#pragma unroll
    for (int ks = 0; ks < 8; ++ks)
      aF[mi][ks] = *(const bf16x8*)(ap + ks * 32);
  }

  float rs[4][4] = {};  // running row sums (per mi, per v)

  stage_half(0, 0);  // prologue: first K-half in flight

  for (int jt = 0; jt < JTILES; ++jt) {
    int j0 = jbase + jt * BJ;
    f32x4 acc[4][4] = {};

    __syncthreads();      // drains half0(jt); half1(jt-1) readers done
    stage_half(jt, 1);    // issue half1(jt) — lands during ks0..3

#pragma unroll
    for (int ks = 0; ks < 4; ++ks) {
      bf16x8 bF[4];
#pragma unroll
      for (int ni = 0; ni < 4; ++ni) {
        int row = wbcol + ni * 16 + (l & 15);
        int kb = ks * 4 + q;               // k-block 0..15 within half
        int blk = kb ^ (row & 15);
        bF[ni] = *(const bf16x8*)(Bs + row * KHALF + blk * 8);
      }
#pragma unroll
      for (int mi = 0; mi < 4; ++mi)
#pragma unroll
        for (int ni = 0; ni < 4; ++ni)
          acc[mi][ni] = __builtin_amdgcn_mfma_f32_16x16x32_bf16(
              aF[mi][ks], bF[ni], acc[mi][ni], 0, 0, 0);
    }

    __syncthreads();      // drains half1(jt); half0(jt) readers done
    int jn = (jt + 1 < JTILES) ? jt + 1 : jt;  // clamp tail prefetch
    stage_half(jn, 0);    // issue half0(jt+1) — lands during ks4..7+epilogue

#pragma unroll
    for (int ks = 4; ks < 8; ++ks) {
      bf16x8 bF[4];
#pragma unroll
      for (int ni = 0; ni < 4; ++ni) {
        int row = wbcol + ni * 16 + (l & 15);
        int kb = (ks - 4) * 4 + q;
        int blk = kb ^ (row & 15);
        bF[ni] = *(const bf16x8*)(Bs + BJ * KHALF + row * KHALF + blk * 8);
      }
#pragma unroll
      for (int mi = 0; mi < 4; ++mi)
#pragma unroll
        for (int ni = 0; ni < 4; ++ni)
          acc[mi][ni] = __builtin_amdgcn_mfma_f32_16x16x32_bf16(
              aF[mi][ks], bF[ni], acc[mi][ni], 0, 0, 0);
    }

    // epilogue (covers the half0(jt+1) prefetch)
    bool dsame = (j0 == i0);
    bool dcross = (j0 == i0 + NROWS);
#pragma unroll
    for (int mi = 0; mi < 4; ++mi)
#pragma unroll
      for (int ni = 0; ni < 4; ++ni)
#pragma unroll
        for (int v = 0; v < 4; ++v) {
          float s = acc[mi][ni][v];          // cosine (rows pre-normalized)
          rs[mi][v] += EXP2F(s * TWOLOG2E);  // exp(s/tau)
          if (dsame | dcross) {
            int li = warow + mi * 16 + q * 4 + v;
            int lj = wbcol + ni * 16 + (l & 15);
            if (li == lj) {
              if (dsame) Dsame[i0 + li] = s;
              else       Dcross[i0 + li] = s;
            }
          }
        }
  }

  // cross-lane (16-wide) reduce, one atomicAdd per row per wave
  float* R = (chunk >= NCHUNK / 2) ? Rhigh : Rlow;
#pragma unroll
  for (int mi = 0; mi < 4; ++mi)
#pragma unroll
    for (int v = 0; v < 4; ++v) {
      float x = rs[mi][v];
      x += __shfl_xor(x, 1, 64);
      x += __shfl_xor(x, 2, 64);
      x += __shfl_xor(x, 4, 64);
      x += __shfl_xor(x, 8, 64);
      if ((l & 15) == 0)
        atomicAdd(&R[i0 + warow + mi * 16 + q * 4 + v], x);
    }
}

__global__ void finalize_kernel(const float* __restrict__ Rlow,
                                const float* __restrict__ Rhigh,
                                const float* __restrict__ Dsame,
                                const float* __restrict__ Dcross,
                                float* __restrict__ out) {
  __shared__ float red[256];
  float acc = 0.f;
  for (int k = threadIdx.x; k < NROWS; k += 256) {
    float d1 = Rlow[k] + Rhigh[k] - EXP2F(Dsame[k] * TWOLOG2E);
    float d2 = Rhigh[NROWS + k] + Rlow[NROWS + k] -
               EXP2F(Dsame[NROWS + k] * TWOLOG2E);
    acc += 0.5f * (logf(d1) + logf(d2)) - 2.f * Dcross[k];
  }
  red[threadIdx.x] = acc;
  __syncthreads();
  for (int s = 128; s > 0; s >>= 1) {
    if (threadIdx.x < s) red[threadIdx.x] += red[threadIdx.x + s];
    __syncthreads();
  }
  if (threadIdx.x == 0) out[0] = red[0] / (float)NROWS;
}

// ---------------------------------------------------------------------------
extern "C" void kernel_launch(void* const* d_in, const int* in_sizes, int n_in,
                              void* d_out, int out_size, void* d_ws,
                              size_t ws_size, hipStream_t stream) {
  const float* z1 = (const float*)d_in[0];
  const float* z2 = (const float*)d_in[1];
  const float* W1 = (const float*)d_in[2];
  const float* b1 = (const float*)d_in[3];
  const float* W2 = (const float*)d_in[4];
  const float* b2 = (const float*)d_in[5];
  float* out = (float*)d_out;

  char* ws = (char*)d_ws;
  size_t off = 0;
  auto alloc = [&](size_t bytes) -> void* {
    void* p = ws + off;
    off += (bytes + 255) & ~(size_t)255;
    return p;
  };
  __bf16* Zb   = (__bf16*)alloc((size_t)TWO_N * KDIM * 2); // reused as Nb
  __bf16* W1b  = (__bf16*)alloc((size_t)KDIM * KDIM * 2);
  __bf16* W2b  = (__bf16*)alloc((size_t)KDIM * KDIM * 2);
  __bf16* Tb   = (__bf16*)alloc((size_t)TWO_N * KDIM * 2);
  float*  H    = (float*)alloc((size_t)TWO_N * KDIM * 4);
  float*  SS   = (float*)alloc((size_t)TWO_N * 4);
  float*  Rlow = (float*)alloc((size_t)TWO_N * 4);
  float*  Rhigh= (float*)alloc((size_t)TWO_N * 4);
  float*  Dsame= (float*)alloc((size_t)TWO_N * 4);
  float*  Dcross=(float*)alloc((size_t)NROWS * 4);
  __bf16* Nb = Zb;  // Zb dead after proj1

  hipMemsetAsync(SS, 0, (size_t)TWO_N * 4, stream);
  hipMemsetAsync(Rlow, 0, (size_t)TWO_N * 4, stream);
  hipMemsetAsync(Rhigh, 0, (size_t)TWO_N * 4, stream);

  int n4z = NROWS * KDIM / 4;   // 786432
  int n4w = KDIM * KDIM / 4;    // 16384
  cast_kernel<<<(n4z + 255) / 256, 256, 0, stream>>>(z1, Zb, n4z);
  cast_kernel<<<(n4z + 255) / 256, 256, 0, stream>>>(z2, Zb + (size_t)NROWS * KDIM, n4z);
  cast_kernel<<<(n4w + 255) / 256, 256, 0, stream>>>(W1, W1b, n4w);
  cast_kernel<<<(n4w + 255) / 256, 256, 0, stream>>>(W2, W2b, n4w);

  proj1_kernel<<<dim3(TWO_N / BM, KDIM / BN), 256, 0, stream>>>(Zb, W1b, b1, Tb);
  proj2_kernel<<<dim3(TWO_N / BM, KDIM / BN), 256, 0, stream>>>(Tb, W2b, b2, H, SS);

  int n4n = TWO_N * KDIM / 4;   // 1572864
  norm_kernel<<<(n4n + 255) / 256, 256, 0, stream>>>(H, SS, Nb);

  sim_kernel<<<(TWO_N / BM) * NCHUNK, 256, 0, stream>>>(Nb, Rlow, Rhigh,
                                                        Dsame, Dcross);
  finalize_kernel<<<1, 256, 0, stream>>>(Rlow, Rhigh, Dsame, Dcross, out);
}

// Round 4
// 506.176 us; speedup vs baseline: 1.4376x; 1.0716x over previous
//
#include <hip/hip_runtime.h>
#include <hip/hip_bf16.h>
#include <hip/hip_fp8.h>

// ---------------------------------------------------------------------------
// GRACE contrastive loss, MI355X.
//  out = mean_k 0.5*(log d1_k + log d2_k) - s12[k,k]/tau
// With M=[n1;n2] (24576x256) everything is row sums of exp(M M^T / tau)
// split by j-half, plus diagonal probes.
//
// R4: sim stage in FP8 e4m3. Normalized rows quantized to fp8; sim kernel
// uses mfma_f32_16x16x32_fp8_fp8 with a 1x4 wave grid (each wave holds all
// 128 A rows in registers: 8x8 fp8 frags = 128 VGPRs), cutting B LDS read
// duplication 2x->1x and all staged bytes 2x. LDS per CU-jt: 384KB -> 128KB.
// Keeps R3's XCD-pinned j-chunks + K-half software pipeline.
// ---------------------------------------------------------------------------

#define NROWS 12288
#define TWO_N 24576
#define KDIM 256
#define BM 128
#define BN 128
#define BK 32
#define BJ 128
#define KHALF 128               /* fp8 bytes per K-half */
#define NCHUNK 8
#define JCHUNK (TWO_N / NCHUNK) /* 3072 */
#define JTILES (JCHUNK / BJ)    /* 24 */
#define LOG2E 1.4426950408889634f
#define TWOLOG2E 2.8853900817779268f /* (1/tau)*log2(e), tau=0.5 */

#if __has_builtin(__builtin_amdgcn_exp2f)
#define EXP2F(x) __builtin_amdgcn_exp2f(x)
#else
#define EXP2F(x) exp2f(x)
#endif

typedef __bf16 bf16x8 __attribute__((ext_vector_type(8)));
typedef __bf16 bf16x4v __attribute__((ext_vector_type(4)));
typedef float f32x4 __attribute__((ext_vector_type(4)));
typedef unsigned char uchar;

typedef const __attribute__((address_space(1))) void* gptr_t;
typedef __attribute__((address_space(3))) void* lptr_t;

// ======== legacy 128x128 bf16 GEMM core (proj1/proj2 only) ================
__device__ __forceinline__ void stage_slab(const __bf16* g, int row0, int kelem,
                                           __bf16* lds, int w, int l) {
#pragma unroll
  for (int t = 0; t < 2; ++t) {
    int chunk = w * 2 + t;
    int r = chunk * 16 + (l >> 2);
    int c = l & 3;
    int src = c ^ (r & 3);
    const __bf16* ga = g + (size_t)(row0 + r) * KDIM + kelem + src * 8;
    __bf16* la = lds + chunk * 512;
    __builtin_amdgcn_global_load_lds((gptr_t)ga, (lptr_t)la, 16, 0, 0);
  }
}

__device__ __forceinline__ bf16x8 read_frag(const __bf16* lds, int rowbase,
                                            int tile, int l) {
  int r = rowbase + tile * 16 + (l & 15);
  int q = l >> 4;
  int blk = q ^ (r & 3);
  return *(const bf16x8*)(lds + r * 32 + blk * 8);
}

__device__ __forceinline__ void gemm_tile_core(const __bf16* A, int arow0,
                                               const __bf16* B, int brow0,
                                               __bf16* As, __bf16* Bs,
                                               f32x4 (&acc)[4][4], int w, int l) {
  const int warow = (w >> 1) * 64;
  const int wbrow = (w & 1) * 64;
#pragma unroll
  for (int ks = 0; ks < KDIM / BK; ++ks) {
    __syncthreads();
    stage_slab(A, arow0, ks * BK, As, w, l);
    stage_slab(B, brow0, ks * BK, Bs, w, l);
    __syncthreads();
    bf16x8 aF[4], bF[4];
#pragma unroll
    for (int mi = 0; mi < 4; ++mi) aF[mi] = read_frag(As, warow, mi, l);
#pragma unroll
    for (int ni = 0; ni < 4; ++ni) bF[ni] = read_frag(Bs, wbrow, ni, l);
#pragma unroll
    for (int mi = 0; mi < 4; ++mi)
#pragma unroll
      for (int ni = 0; ni < 4; ++ni)
        acc[mi][ni] = __builtin_amdgcn_mfma_f32_16x16x32_bf16(
            aF[mi], bF[ni], acc[mi][ni], 0, 0, 0);
  }
}

// ---------------------------------------------------------------------------
__global__ void cast_kernel(const float* __restrict__ src,
                            __bf16* __restrict__ dst, int n4) {
  int i = blockIdx.x * blockDim.x + threadIdx.x;
  if (i >= n4) return;
  float4 v = *(const float4*)(src + (size_t)i * 4);
  bf16x4v o;
  o[0] = (__bf16)v.x; o[1] = (__bf16)v.y; o[2] = (__bf16)v.z; o[3] = (__bf16)v.w;
  *(bf16x4v*)(dst + (size_t)i * 4) = o;
}

// T = ELU(Z @ W1^T + b1), stored bf16
__global__ __launch_bounds__(256, 2) void proj1_kernel(
    const __bf16* __restrict__ Zb, const __bf16* __restrict__ W1b,
    const float* __restrict__ b1, __bf16* __restrict__ Tb) {
  __shared__ __align__(16) __bf16 As[BM * BK];
  __shared__ __align__(16) __bf16 Bs[BN * BK];
  int w = threadIdx.x >> 6, l = threadIdx.x & 63;
  int i0 = blockIdx.x * BM, j0 = blockIdx.y * BN;
  int warow = (w >> 1) * 64, wbrow = (w & 1) * 64;
  f32x4 acc[4][4] = {};
  gemm_tile_core(Zb, i0, W1b, j0, As, Bs, acc, w, l);
  float bias[4];
#pragma unroll
  for (int ni = 0; ni < 4; ++ni) bias[ni] = b1[j0 + wbrow + ni * 16 + (l & 15)];
#pragma unroll
  for (int mi = 0; mi < 4; ++mi)
#pragma unroll
    for (int ni = 0; ni < 4; ++ni)
#pragma unroll
      for (int v = 0; v < 4; ++v) {
        int row = i0 + warow + mi * 16 + (l >> 4) * 4 + v;
        int col = j0 + wbrow + ni * 16 + (l & 15);
        float x = acc[mi][ni][v] + bias[ni];
        x = x > 0.f ? x : (EXP2F(x * LOG2E) - 1.f);  // ELU
        Tb[(size_t)row * KDIM + col] = (__bf16)x;
      }
}

// H = T @ W2^T + b2 (fp32), plus per-row sum of squares via atomics
__global__ __launch_bounds__(256, 2) void proj2_kernel(
    const __bf16* __restrict__ Tb, const __bf16* __restrict__ W2b,
    const float* __restrict__ b2, float* __restrict__ H,
    float* __restrict__ SS) {
  __shared__ __align__(16) __bf16 As[BM * BK];
  __shared__ __align__(16) __bf16 Bs[BN * BK];
  int w = threadIdx.x >> 6, l = threadIdx.x & 63;
  int i0 = blockIdx.x * BM, j0 = blockIdx.y * BN;
  int warow = (w >> 1) * 64, wbrow = (w & 1) * 64;
  f32x4 acc[4][4] = {};
  gemm_tile_core(Tb, i0, W2b, j0, As, Bs, acc, w, l);
  float bias[4];
#pragma unroll
  for (int ni = 0; ni < 4; ++ni) bias[ni] = b2[j0 + wbrow + ni * 16 + (l & 15)];
  float ss[4][4] = {};
#pragma unroll
  for (int mi = 0; mi < 4; ++mi)
#pragma unroll
    for (int ni = 0; ni < 4; ++ni)
#pragma unroll
      for (int v = 0; v < 4; ++v) {
        int row = i0 + warow + mi * 16 + (l >> 4) * 4 + v;
        int col = j0 + wbrow + ni * 16 + (l & 15);
        float x = acc[mi][ni][v] + bias[ni];
        H[(size_t)row * KDIM + col] = x;
        ss[mi][v] += x * x;
      }
#pragma unroll
  for (int mi = 0; mi < 4; ++mi)
#pragma unroll
    for (int v = 0; v < 4; ++v) {
      float x = ss[mi][v];
      x += __shfl_xor(x, 1, 64);
      x += __shfl_xor(x, 2, 64);
      x += __shfl_xor(x, 4, 64);
      x += __shfl_xor(x, 8, 64);
      if ((l & 15) == 0)
        atomicAdd(&SS[i0 + warow + mi * 16 + (l >> 4) * 4 + v], x);
    }
}

// pack 4 floats -> 4 fp8 e4m3 bytes
__device__ __forceinline__ unsigned int pack4_fp8(float a, float b, float c,
                                                  float d) {
#if __has_builtin(__builtin_amdgcn_cvt_pk_fp8_f32)
  int v = 0;
  v = __builtin_amdgcn_cvt_pk_fp8_f32(a, b, v, false);
  v = __builtin_amdgcn_cvt_pk_fp8_f32(c, d, v, true);
  return (unsigned int)v;
#else
  __hip_fp8_e4m3 qa(a), qb(b), qc(c), qd(d);
  return (unsigned int)qa.__x | ((unsigned int)qb.__x << 8) |
         ((unsigned int)qc.__x << 16) | ((unsigned int)qd.__x << 24);
#endif
}

// Nq = fp8(H * rsqrt(SS[row])) — 8 elements per thread
__global__ void norm_kernel(const float* __restrict__ H,
                            const float* __restrict__ SS,
                            uchar* __restrict__ Nq) {
  int i = blockIdx.x * blockDim.x + threadIdx.x;
  size_t idx = (size_t)i * 8;
  if (idx >= (size_t)TWO_N * KDIM) return;
  int row = (int)(idx >> 8);
  float inv = rsqrtf(SS[row]);
  float4 h0 = *(const float4*)(H + idx);
  float4 h1 = *(const float4*)(H + idx + 4);
  uint2 o;
  o.x = pack4_fp8(h0.x * inv, h0.y * inv, h0.z * inv, h0.w * inv);
  o.y = pack4_fp8(h1.x * inv, h1.y * inv, h1.z * inv, h1.w * inv);
  *(uint2*)(Nq + idx) = o;
}

// ======== R4 sim kernel (fp8) =============================================
// grid = 1536 1D blocks. chunk = blockIdx&7 (XCD-pinned), itile = blockIdx>>3.
// 1x4 wave grid: each wave computes all 128 A rows x 32 B cols. A frags in
// 128 VGPRs (fp8). B: 128 rows staged per jt in two 16KB K-halves,
// software-pipelined. ds_read_b64 frag reads, XOR-by-row swizzle.
__global__ __launch_bounds__(256, 2) void sim_kernel(
    const uchar* __restrict__ Nq, float* __restrict__ Rlow,
    float* __restrict__ Rhigh, float* __restrict__ Dsame,
    float* __restrict__ Dcross) {
  __shared__ __align__(16) uchar Bs[2 * BJ * KHALF];  // 2 x 16KB
  int tid = threadIdx.x;
  int w = tid >> 6, l = tid & 63;
  int q = l >> 4;
  int b = blockIdx.x;
  int chunk = b & 7;           // XCD id under round-robin dispatch
  int i0 = (b >> 3) * BM;
  int jbase = chunk * JCHUNK;
  int wbcol = w * 32;          // B cols of this wave: wbcol..wbcol+31

  // stage one 16KB K-half of a 128-row j-tile; source-side XOR swizzle
  // (8 16B-blocks per row-half; slot c holds global block c ^ (r&7)).
  auto stage_half = [&](int jt, int hf) {
    int j0 = jbase + jt * BJ;
#pragma unroll
    for (int t = 0; t < 4; ++t) {
      int ch = w * 4 + t;            // wave-uniform chunk 0..15 (1KB each)
      int r = ch * 8 + (l >> 3);     // row 0..127 (8 rows per chunk)
      int c = l & 7;                 // dest 16B-block slot
      int src = c ^ (r & 7);         // global k-block landing in slot c
      const uchar* ga = Nq + (size_t)(j0 + r) * KDIM + hf * KHALF + src * 16;
      uchar* la = Bs + hf * (BJ * KHALF) + ch * 1024;  // uniform base
      __builtin_amdgcn_global_load_lds((gptr_t)ga, (lptr_t)la, 16, 0, 0);
    }
  };

  // ---- A fragments in registers: aF[mi][ks], 64 x 8B = 128 VGPRs ----
  // fp8 16x16x32 A layout: lane holds row (l&15), k = q*8 + 0..7 (bytes).
  long aF[8][8];
#pragma unroll
  for (int mi = 0; mi < 8; ++mi) {
    const uchar* ap = Nq + (size_t)(i0 + mi * 16 + (l & 15)) * KDIM + q * 8;
#pragma unroll
    for (int ks = 0; ks < 8; ++ks)
      aF[mi][ks] = *(const long*)(ap + ks * 32);
  }

  float rs[8][4] = {};  // running row sums (per mi, per v)

  stage_half(0, 0);  // prologue: first K-half in flight

  for (int jt = 0; jt < JTILES; ++jt) {
    int j0 = jbase + jt * BJ;
    f32x4 acc[8][2] = {};

    __syncthreads();      // drains half0(jt); half1(jt-1) readers done
    stage_half(jt, 1);    // issue half1(jt) — lands during ks0..3

#pragma unroll
    for (int ks = 0; ks < 4; ++ks) {
      long bF[2];
#pragma unroll
      for (int nj = 0; nj < 2; ++nj) {
        int row = wbcol + nj * 16 + (l & 15);
        int slot = (ks * 2 + (q >> 1)) ^ (row & 7);
        bF[nj] = *(const long*)(Bs + row * KHALF + slot * 16 + (q & 1) * 8);
      }
#pragma unroll
      for (int mi = 0; mi < 8; ++mi)
#pragma unroll
        for (int nj = 0; nj < 2; ++nj)
          acc[mi][nj] = __builtin_amdgcn_mfma_f32_16x16x32_fp8_fp8(
              aF[mi][ks], bF[nj], acc[mi][nj], 0, 0, 0);
    }

    __syncthreads();      // drains half1(jt); half0(jt) readers done
    int jn = (jt + 1 < JTILES) ? jt + 1 : jt;  // clamp tail prefetch
    stage_half(jn, 0);    // issue half0(jt+1) — lands during ks4..7+epilogue

#pragma unroll
    for (int ks = 4; ks < 8; ++ks) {
      long bF[2];
#pragma unroll
      for (int nj = 0; nj < 2; ++nj) {
        int row = wbcol + nj * 16 + (l & 15);
        int slot = ((ks - 4) * 2 + (q >> 1)) ^ (row & 7);
        bF[nj] = *(const long*)(Bs + BJ * KHALF + row * KHALF + slot * 16 +
                                (q & 1) * 8);
      }
#pragma unroll
      for (int mi = 0; mi < 8; ++mi)
#pragma unroll
        for (int nj = 0; nj < 2; ++nj)
          acc[mi][nj] = __builtin_amdgcn_mfma_f32_16x16x32_fp8_fp8(
              aF[mi][ks], bF[nj], acc[mi][nj], 0, 0, 0);
    }

    // epilogue (covers the half0(jt+1) prefetch)
    bool dsame = (j0 == i0);
    bool dcross = (j0 == i0 + NROWS);
#pragma unroll
    for (int mi = 0; mi < 8; ++mi)
#pragma unroll
      for (int nj = 0; nj < 2; ++nj)
#pragma unroll
        for (int v = 0; v < 4; ++v) {
          float s = acc[mi][nj][v];          // cosine (rows pre-normalized)
          rs[mi][v] += EXP2F(s * TWOLOG2E);  // exp(s/tau)
          if (dsame | dcross) {
            int li = mi * 16 + q * 4 + v;
            int lj = wbcol + nj * 16 + (l & 15);
            if (li == lj) {
              if (dsame) Dsame[i0 + li] = s;
              else       Dcross[i0 + li] = s;
            }
          }
        }
  }

  // cross-lane (16-wide) reduce, one atomicAdd per row per wave
  float* R = (chunk >= NCHUNK / 2) ? Rhigh : Rlow;
#pragma unroll
  for (int mi = 0; mi < 8; ++mi)
#pragma unroll
    for (int v = 0; v < 4; ++v) {
      float x = rs[mi][v];
      x += __shfl_xor(x, 1, 64);
      x += __shfl_xor(x, 2, 64);
      x += __shfl_xor(x, 4, 64);
      x += __shfl_xor(x, 8, 64);
      if ((l & 15) == 0)
        atomicAdd(&R[i0 + mi * 16 + q * 4 + v], x);
    }
}

__global__ void finalize_kernel(const float* __restrict__ Rlow,
                                const float* __restrict__ Rhigh,
                                const float* __restrict__ Dsame,
                                const float* __restrict__ Dcross,
                                float* __restrict__ out) {
  __shared__ float red[256];
  float acc = 0.f;
  for (int k = threadIdx.x; k < NROWS; k += 256) {
    float d1 = Rlow[k] + Rhigh[k] - EXP2F(Dsame[k] * TWOLOG2E);
    float d2 = Rhigh[NROWS + k] + Rlow[NROWS + k] -
               EXP2F(Dsame[NROWS + k] * TWOLOG2E);
    acc += 0.5f * (logf(d1) + logf(d2)) - 2.f * Dcross[k];
  }
  red[threadIdx.x] = acc;
  __syncthreads();
  for (int s = 128; s > 0; s >>= 1) {
    if (threadIdx.x < s) red[threadIdx.x] += red[threadIdx.x + s];
    __syncthreads();
  }
  if (threadIdx.x == 0) out[0] = red[0] / (float)NROWS;
}

// ---------------------------------------------------------------------------
extern "C" void kernel_launch(void* const* d_in, const int* in_sizes, int n_in,
                              void* d_out, int out_size, void* d_ws,
                              size_t ws_size, hipStream_t stream) {
  const float* z1 = (const float*)d_in[0];
  const float* z2 = (const float*)d_in[1];
  const float* W1 = (const float*)d_in[2];
  const float* b1 = (const float*)d_in[3];
  const float* W2 = (const float*)d_in[4];
  const float* b2 = (const float*)d_in[5];
  float* out = (float*)d_out;

  char* ws = (char*)d_ws;
  size_t off = 0;
  auto alloc = [&](size_t bytes) -> void* {
    void* p = ws + off;
    off += (bytes + 255) & ~(size_t)255;
    return p;
  };
  __bf16* Zb   = (__bf16*)alloc((size_t)TWO_N * KDIM * 2); // reused as Nq
  __bf16* W1b  = (__bf16*)alloc((size_t)KDIM * KDIM * 2);
  __bf16* W2b  = (__bf16*)alloc((size_t)KDIM * KDIM * 2);
  __bf16* Tb   = (__bf16*)alloc((size_t)TWO_N * KDIM * 2);
  float*  H    = (float*)alloc((size_t)TWO_N * KDIM * 4);
  float*  SS   = (float*)alloc((size_t)TWO_N * 4);
  float*  Rlow = (float*)alloc((size_t)TWO_N * 4);
  float*  Rhigh= (float*)alloc((size_t)TWO_N * 4);
  float*  Dsame= (float*)alloc((size_t)TWO_N * 4);
  float*  Dcross=(float*)alloc((size_t)NROWS * 4);
  uchar*  Nq = (uchar*)Zb;  // Zb dead after proj1; fp8 fits in its footprint

  hipMemsetAsync(SS, 0, (size_t)TWO_N * 4, stream);
  hipMemsetAsync(Rlow, 0, (size_t)TWO_N * 4, stream);
  hipMemsetAsync(Rhigh, 0, (size_t)TWO_N * 4, stream);

  int n4z = NROWS * KDIM / 4;   // 786432
  int n4w = KDIM * KDIM / 4;    // 16384
  cast_kernel<<<(n4z + 255) / 256, 256, 0, stream>>>(z1, Zb, n4z);
  cast_kernel<<<(n4z + 255) / 256, 256, 0, stream>>>(z2, Zb + (size_t)NROWS * KDIM, n4z);
  cast_kernel<<<(n4w + 255) / 256, 256, 0, stream>>>(W1, W1b, n4w);
  cast_kernel<<<(n4w + 255) / 256, 256, 0, stream>>>(W2, W2b, n4w);

  proj1_kernel<<<dim3(TWO_N / BM, KDIM / BN), 256, 0, stream>>>(Zb, W1b, b1, Tb);
  proj2_kernel<<<dim3(TWO_N / BM, KDIM / BN), 256, 0, stream>>>(Tb, W2b, b2, H, SS);

  int n8n = TWO_N * KDIM / 8;   // 786432
  norm_kernel<<<(n8n + 255) / 256, 256, 0, stream>>>(H, SS, Nq);

  sim_kernel<<<(TWO_N / BM) * NCHUNK, 256, 0, stream>>>(Nq, Rlow, Rhigh,
                                                        Dsame, Dcross);
  finalize_kernel<<<1, 256, 0, stream>>>(Rlow, Rhigh, Dsame, Dcross, out);
}